// Round 2
// baseline (410.401 us; speedup 1.0000x reference)
//
#include <hip/hip_runtime.h>
#include <hip/hip_bf16.h>

using short8 = __attribute__((ext_vector_type(8))) short;
using f32x4  = __attribute__((ext_vector_type(4))) float;

#define SEQ   2048
#define DM    1024
#define NHEAD 16
#define MB    1048576

// async global->LDS, 16B per lane. LDS dest must be linear in lane (base + lane*16);
// the XOR swizzle is applied to the GLOBAL source address instead (involution =>
// identical LDS image to the old ds_write path).
#define GLD16(GP, LP) __builtin_amdgcn_global_load_lds(                      \
    (const __attribute__((address_space(1))) void*)(GP),                     \
    (__attribute__((address_space(3))) void*)(LP), 16, 0, 0)

static __device__ __forceinline__ short f2bf(float f) {
    union { __hip_bfloat16 b; short s; } u;
    u.b = __float2bfloat16(f);
    return u.s;
}
static __device__ __forceinline__ f32x4 mfma_bf16(short8 a, short8 b, f32x4 c) {
    return __builtin_amdgcn_mfma_f32_16x16x32_bf16(a, b, c, 0, 0, 0);
}

// ---------------------------------------------------------------------------
// K0: fp32 -> bf16 conversion of q,k,v,wq,wk,wv,wo into ws (10M elems), plus
// RoPE cos/sin tables [2048][32] fp32.
// ---------------------------------------------------------------------------
__global__ __launch_bounds__(256) void prep_kernel(
    const float* __restrict__ q, const float* __restrict__ k, const float* __restrict__ v,
    const float* __restrict__ wq, const float* __restrict__ wk, const float* __restrict__ wv,
    const float* __restrict__ wo, short* __restrict__ bf,
    float* __restrict__ cosT, float* __restrict__ sinT)
{
    long t = (long)blockIdx.x * 256 + threadIdx.x;
    if (t < 1310720) {                       // 10485760 / 8 elements per thread
        long e0 = t * 8;
        const float* src; long off;
        if      (e0 < 2L*MB) { src = q;  off = e0; }
        else if (e0 < 4L*MB) { src = k;  off = e0 - 2L*MB; }
        else if (e0 < 6L*MB) { src = v;  off = e0 - 4L*MB; }
        else if (e0 < 7L*MB) { src = wq; off = e0 - 6L*MB; }
        else if (e0 < 8L*MB) { src = wk; off = e0 - 7L*MB; }
        else if (e0 < 9L*MB) { src = wv; off = e0 - 8L*MB; }
        else                 { src = wo; off = e0 - 9L*MB; }
        float4 a = *(const float4*)(src + off);
        float4 b = *(const float4*)(src + off + 4);
        short8 o;
        o[0]=f2bf(a.x); o[1]=f2bf(a.y); o[2]=f2bf(a.z); o[3]=f2bf(a.w);
        o[4]=f2bf(b.x); o[5]=f2bf(b.y); o[6]=f2bf(b.z); o[7]=f2bf(b.w);
        *(short8*)(bf + e0) = o;
    } else {
        long tt = t - 1310720;               // < 65536 = 2048*32
        int s = (int)(tt >> 5), j = (int)(tt & 31);
        float invf = __expf(-(float)j * (9.210340371976184f / 32.0f)); // 10000^(-j/32)
        float arg = (float)s * invf;
        cosT[tt] = cosf(arg);
        sinT[tt] = sinf(arg);
    }
}

// ---------------------------------------------------------------------------
// QKV GEMM  C[2048,1024] = X[2048,1024] @ W[1024,1024]^T  (bf16 NT).
// 128x128 block tile, 4 waves 2x2, wave 64x64 (one head wide).
// Staging via global_load_lds (linear LDS dest, source pre-swizzled).
// Epilogue: z<2 (Q,K) applies RoPE in fp32 pre-rounding, writes [h][s][d];
// z==2 (V) writes transposed [h][d][s].
// ---------------------------------------------------------------------------
__global__ __launch_bounds__(256, 2) void gemm_qkv(
    short* __restrict__ wsbf, const float* __restrict__ cosT,
    const float* __restrict__ sinT)
{
    __shared__ short As[128 * 64];
    __shared__ short Bs[128 * 64];
    const int tid  = threadIdx.x;
    const int lane = tid & 63;
    const int wave = tid >> 6;
    const int q4   = lane >> 4;
    const int l16  = lane & 15;
    const int wm   = wave >> 1;
    const int wn   = wave & 1;
    const int m0   = blockIdx.y * 128;
    const int n0   = blockIdx.x * 128;
    const int z    = blockIdx.z;

    const short* A = wsbf + (size_t)z * (2*MB);
    const short* W = wsbf + 6*(size_t)MB + (size_t)z * MB;

    f32x4 zero = {0.f, 0.f, 0.f, 0.f};
    f32x4 acc[4][4];
    #pragma unroll
    for (int i = 0; i < 4; ++i)
        #pragma unroll
        for (int j = 0; j < 4; ++j) acc[i][j] = zero;

    const int r8 = tid >> 3, c8 = tid & 7;

    for (int k0 = 0; k0 < 1024; k0 += 64) {
        __syncthreads();
        #pragma unroll
        for (int r = 0; r < 4; ++r) {
            int row = r*32 + r8;
            int sw  = c8 ^ (row & 7);
            GLD16(A + (size_t)(m0+row)*1024 + k0 + sw*8, &As[(r*256 + tid)*8]);
            GLD16(W + (size_t)(n0+row)*1024 + k0 + sw*8, &Bs[(r*256 + tid)*8]);
        }
        __syncthreads();                 // implicit vmcnt(0) drains the loads
        #pragma unroll
        for (int kk = 0; kk < 2; ++kk) {
            short8 af[4], bfr[4];
            #pragma unroll
            for (int i = 0; i < 4; ++i) {
                int ra = wm*64 + i*16 + l16;
                af[i]  = *(const short8*)&As[ra*64 + (((kk*4+q4) ^ (ra&7))*8)];
                int rb = wn*64 + i*16 + l16;
                bfr[i] = *(const short8*)&Bs[rb*64 + (((kk*4+q4) ^ (rb&7))*8)];
            }
            #pragma unroll
            for (int i = 0; i < 4; ++i)
                #pragma unroll
                for (int j = 0; j < 4; ++j)
                    acc[i][j] = mfma_bf16(af[i], bfr[j], acc[i][j]);
        }
    }

    const int h = (n0 >> 6) + wn;   // wave spans cols [n0+wn*64, +64) = head h
    if (z < 2) {
        short* dst = wsbf + (size_t)(10 + 2*z) * MB;   // [h][s][64]
        #pragma unroll
        for (int i = 0; i < 4; ++i) {
            #pragma unroll
            for (int jj = 0; jj < 4; ++jj) {
                int s = m0 + wm*64 + i*16 + q4*4 + jj;
                float c0 = cosT[(s<<5) + l16],      s0 = sinT[(s<<5) + l16];
                float c1 = cosT[(s<<5) + 16 + l16], s1 = sinT[(s<<5) + 16 + l16];
                float v0 = acc[i][0][jj], v1 = acc[i][1][jj];
                float v2 = acc[i][2][jj], v3 = acc[i][3][jj];
                size_t base = ((size_t)h*SEQ + s)*64;
                dst[base + l16]      = f2bf(v0*c0 - v2*s0);
                dst[base + 16 + l16] = f2bf(v1*c1 - v3*s1);
                dst[base + 32 + l16] = f2bf(v2*c0 + v0*s0);
                dst[base + 48 + l16] = f2bf(v3*c1 + v1*s1);
            }
        }
    } else {
        short* dst = wsbf + (size_t)14 * MB;           // V transposed [h][d][s]
        #pragma unroll
        for (int i = 0; i < 4; ++i)
            #pragma unroll
            for (int j = 0; j < 4; ++j)
                #pragma unroll
                for (int jj = 0; jj < 4; ++jj) {
                    int s = m0 + wm*64 + i*16 + q4*4 + jj;
                    int d = j*16 + l16;
                    dst[((size_t)h*64 + d)*SEQ + s] = f2bf(acc[i][j][jj]);
                }
    }
}

// ---------------------------------------------------------------------------
// Fused attention: block = 64 q-rows x 1 head, wave owns 16 q-rows.
// Pipelined: K double-buffered; at top of each kt we issue V(kt)+K(kt+1) via
// global_load_lds, compute S(kt) from Ks[cur] meanwhile, then counted
// vmcnt(4) (V landed, K still in flight) + raw s_barrier -> PV, then
// vmcnt(0)+barrier. Sweep 2 prefetches K with vmcnt(32) (in-order vmcnt:
// waiting to <=32 outstanding retires the 4 prefetch loads issued before the
// 32 attn stores). Q fragments read from LDS ONCE (kt-invariant).
// ---------------------------------------------------------------------------
__global__ __launch_bounds__(256, 2) void attn_kernel(
    const short* __restrict__ wsbf, short* __restrict__ ctxout,
    float* __restrict__ attn)
{
    __shared__ short Qs[64 * 64];
    __shared__ short Ks[2][128 * 64];  // double-buffered K tile [key][d]
    __shared__ short Vs[64 * 128];     // V tile [d][key]
    __shared__ short Ps[4][16 * 128];  // per-wave P tile [qrow][key], swizzled
    const int tid = threadIdx.x, lane = tid & 63, wave = tid >> 6;
    const int q4 = lane >> 4, l16 = lane & 15;
    const int h = blockIdx.y, qt0 = blockIdx.x * 64;
    const short* Qg = wsbf + (size_t)10*MB + ((size_t)h*SEQ + qt0)*64;
    const short* Kg = wsbf + (size_t)12*MB + (size_t)h*SEQ*64;
    const short* Vg = wsbf + (size_t)14*MB + (size_t)h*64*SEQ;

    const int r8  = tid >> 3, c8  = tid & 7;   // K/Q staging coords
    const int r16 = tid >> 4, c16 = tid & 15;  // V staging coords

    auto stageK = [&](int kt, short* buf) {
        #pragma unroll
        for (int r = 0; r < 4; ++r) {
            int row = r*32 + r8;
            int sw  = c8 ^ (row & 7);
            GLD16(Kg + (size_t)(kt*128 + row)*64 + sw*8, buf + (r*256 + tid)*8);
        }
    };
    auto stageV = [&](int kt) {
        #pragma unroll
        for (int r = 0; r < 4; ++r) {
            int row = r*16 + r16;
            int sw  = c16 ^ (row & 7);
            GLD16(Vg + (size_t)row*SEQ + kt*128 + sw*8, &Vs[(r*256 + tid)*8]);
        }
    };

    // prologue: Q + K(0)
    #pragma unroll
    for (int r = 0; r < 2; ++r) {
        int row = r*32 + r8;
        int sw  = c8 ^ (row & 7);
        GLD16(Qg + (size_t)row*64 + sw*8, &Qs[(r*256 + tid)*8]);
    }
    stageK(0, Ks[0]);
    __syncthreads();                     // vmcnt(0) drain + barrier

    const int ra = wave*16 + l16;
    short8 a_q[2];                       // kt-invariant Q fragments
    #pragma unroll
    for (int kk = 0; kk < 2; ++kk)
        a_q[kk] = *(const short8*)&Qs[ra*64 + (((kk*4+q4) ^ (ra&7))*8)];

    f32x4 zero = {0.f, 0.f, 0.f, 0.f};
    f32x4 ctx[4] = {zero, zero, zero, zero};
    float rs[4] = {0.f, 0.f, 0.f, 0.f};
    const int frw = ((l16 & 7) + 2*(l16 >> 3)) & 7;   // Ps read-row swizzle

    for (int kt = 0; kt < 16; ++kt) {
        const short* Kb = (kt & 1) ? Ks[1] : Ks[0];
        short*       Kn = (kt & 1) ? Ks[0] : Ks[1];
        stageV(kt);                      // needed at mid-barrier
        if (kt < 15) stageK(kt + 1, Kn); // needed at end-barrier
        // S phase: p unnormalized; rowsum; stash to Ps
        #pragma unroll
        for (int nt = 0; nt < 8; ++nt) {
            f32x4 acc = zero;
            #pragma unroll
            for (int kk = 0; kk < 2; ++kk) {
                int rb = nt*16 + l16;
                short8 b = *(const short8*)&Kb[rb*64 + (((kk*4+q4) ^ (rb&7))*8)];
                acc = mfma_bf16(a_q[kk], b, acc);
            }
            #pragma unroll
            for (int jj = 0; jj < 4; ++jj) {
                float p = __expf(acc[jj] * 0.125f);
                rs[jj] += p;
                int prow = q4*4 + jj;
                int col  = nt*16 + l16;
                int fr   = ((prow & 7) + 2*(prow >> 3)) & 7;
                int phys = (col >> 3) ^ fr;
                Ps[wave][prow*128 + phys*8 + (col & 7)] = f2bf(p);
            }
        }
        // V = oldest 4 vmem ops of this iteration; K(kt+1) stays in flight.
        if (kt < 15) asm volatile("s_waitcnt vmcnt(4) lgkmcnt(0)" ::: "memory");
        else         asm volatile("s_waitcnt vmcnt(0) lgkmcnt(0)" ::: "memory");
        __builtin_amdgcn_s_barrier();
        // PV phase (Ps is per-wave)
        #pragma unroll
        for (int kks = 0; kks < 4; ++kks) {
            short8 a = *(const short8*)&Ps[wave][l16*128 + (((kks*4+q4) ^ frw)*8)];
            #pragma unroll
            for (int dt = 0; dt < 4; ++dt) {
                int rv = dt*16 + l16;
                short8 b = *(const short8*)&Vs[rv*128 + (((kks*4+q4) ^ (rv&7))*8)];
                ctx[dt] = mfma_bf16(a, b, ctx[dt]);
            }
        }
        // K(kt+1) landed + all LDS reads retired before buffers are rewritten
        asm volatile("s_waitcnt vmcnt(0) lgkmcnt(0)" ::: "memory");
        __builtin_amdgcn_s_barrier();
    }

    // rowsum reduce across the 16 lanes sharing each row, then normalize
    #pragma unroll
    for (int jj = 0; jj < 4; ++jj)
        #pragma unroll
        for (int m = 1; m < 16; m <<= 1)
            rs[jj] += __shfl_xor(rs[jj], m);
    float irs[4];
    #pragma unroll
    for (int jj = 0; jj < 4; ++jj) irs[jj] = 1.0f / rs[jj];

    const int qbase = qt0 + wave*16 + q4*4;
    #pragma unroll
    for (int dt = 0; dt < 4; ++dt)
        #pragma unroll
        for (int jj = 0; jj < 4; ++jj)
            ctxout[(size_t)(qbase + jj)*1024 + h*64 + dt*16 + l16] = f2bf(ctx[dt][jj] * irs[jj]);

    // Sweep 2: recompute S, write normalized attn (K pipelined, 1 barrier/kt)
    stageK(0, Ks[0]);                    // Ks[0] last read at kt=14: safe
    asm volatile("s_waitcnt vmcnt(0) lgkmcnt(0)" ::: "memory");
    __builtin_amdgcn_s_barrier();

    float* arow = attn + (size_t)h*SEQ*SEQ;
    for (int kt = 0; kt < 16; ++kt) {
        const short* Kb = (kt & 1) ? Ks[1] : Ks[0];
        short*       Kn = (kt & 1) ? Ks[0] : Ks[1];
        if (kt < 15) stageK(kt + 1, Kn);
        #pragma unroll
        for (int nt = 0; nt < 8; ++nt) {
            f32x4 acc = zero;
            #pragma unroll
            for (int kk = 0; kk < 2; ++kk) {
                int rb = nt*16 + l16;
                short8 b = *(const short8*)&Kb[rb*64 + (((kk*4+q4) ^ (rb&7))*8)];
                acc = mfma_bf16(a_q[kk], b, acc);
            }
            #pragma unroll
            for (int jj = 0; jj < 4; ++jj)
                arow[(size_t)(qbase + jj)*SEQ + kt*128 + nt*16 + l16] =
                    __expf(acc[jj] * 0.125f) * irs[jj];
        }
        // outstanding (oldest first): <=32 stores(kt-1), 4 prefetch-K, 32 stores(kt).
        // vmcnt in-order => waiting to <=32 retires the prefetch; stores keep flowing.
        asm volatile("s_waitcnt vmcnt(32) lgkmcnt(0)" ::: "memory");
        __builtin_amdgcn_s_barrier();
    }
}

// ---------------------------------------------------------------------------
// Output projection: out[2048,1024] = ctx[2048,1024] @ wo[1024,1024]^T + b.
// 128x64 block tile (256 blocks for CU fill), 4 waves stacked over rows.
// Staging via global_load_lds (linear dest, pre-swizzled source).
// ---------------------------------------------------------------------------
__global__ __launch_bounds__(256, 2) void gemm_out(
    const short* __restrict__ wsbf, const float* __restrict__ bo,
    float* __restrict__ out)
{
    __shared__ short As[128 * 64];
    __shared__ short Bs[64 * 64];
    const int tid = threadIdx.x, lane = tid & 63, wave = tid >> 6;
    const int q4 = lane >> 4, l16 = lane & 15;
    const int m0 = blockIdx.y * 128, n0 = blockIdx.x * 64;
    const short* A = wsbf + 16*(size_t)MB;    // ctx bf16 [s][1024]
    const short* W = wsbf + 9*(size_t)MB;     // wo bf16 [n][k]

    f32x4 zero = {0.f, 0.f, 0.f, 0.f};
    f32x4 acc[2][4];
    #pragma unroll
    for (int i = 0; i < 2; ++i)
        #pragma unroll
        for (int j = 0; j < 4; ++j) acc[i][j] = zero;

    const int r8 = tid >> 3, c8 = tid & 7;

    for (int k0 = 0; k0 < 1024; k0 += 64) {
        __syncthreads();
        #pragma unroll
        for (int r = 0; r < 4; ++r) {
            int row = r*32 + r8;
            int sw  = c8 ^ (row & 7);
            GLD16(A + (size_t)(m0+row)*1024 + k0 + sw*8, &As[(r*256 + tid)*8]);
        }
        #pragma unroll
        for (int r = 0; r < 2; ++r) {
            int row = r*32 + r8;
            int sw  = c8 ^ (row & 7);
            GLD16(W + (size_t)(n0+row)*1024 + k0 + sw*8, &Bs[(r*256 + tid)*8]);
        }
        __syncthreads();
        #pragma unroll
        for (int kk = 0; kk < 2; ++kk) {
            short8 af[2], bfr[4];
            #pragma unroll
            for (int i = 0; i < 2; ++i) {
                int ra = wave*32 + i*16 + l16;
                af[i] = *(const short8*)&As[ra*64 + (((kk*4+q4) ^ (ra&7))*8)];
            }
            #pragma unroll
            for (int j = 0; j < 4; ++j) {
                int rb = j*16 + l16;
                bfr[j] = *(const short8*)&Bs[rb*64 + (((kk*4+q4) ^ (rb&7))*8)];
            }
            #pragma unroll
            for (int i = 0; i < 2; ++i)
                #pragma unroll
                for (int j = 0; j < 4; ++j)
                    acc[i][j] = mfma_bf16(af[i], bfr[j], acc[i][j]);
        }
    }

    #pragma unroll
    for (int i = 0; i < 2; ++i)
        #pragma unroll
        for (int j = 0; j < 4; ++j)
            #pragma unroll
            for (int jj = 0; jj < 4; ++jj) {
                int gr = m0 + wave*32 + i*16 + q4*4 + jj;
                int gc = n0 + j*16 + l16;
                out[(size_t)gr*1024 + gc] = acc[i][j][jj] + bo[gc];
            }
}

// ---------------------------------------------------------------------------
// ws layout (bf16 elements):
//   0..2M q | 2M..4M k | 4M..6M v | 6M..7M wq | 7M..8M wk | 8M..9M wv | 9M..10M wo
//   10M..12M Qh [h][s][d] | 12M..14M Kh | 14M..16M Vt [h][d][s] | 16M..18M ctx
//   byte 36MB+: cosT fp32[65536], sinT fp32[65536]
// ---------------------------------------------------------------------------
extern "C" void kernel_launch(void* const* d_in, const int* in_sizes, int n_in,
                              void* d_out, int out_size, void* d_ws, size_t ws_size,
                              hipStream_t stream)
{
    const float* q  = (const float*)d_in[0];
    const float* k  = (const float*)d_in[1];
    const float* v  = (const float*)d_in[2];
    const float* wq = (const float*)d_in[3];
    const float* wk = (const float*)d_in[4];
    const float* wv = (const float*)d_in[5];
    const float* wo = (const float*)d_in[6];
    const float* bo = (const float*)d_in[7];

    short* wsbf = (short*)d_ws;
    float* cosT = (float*)((char*)d_ws + (size_t)36*MB);
    float* sinT = cosT + 65536;
    float* out  = (float*)d_out;
    float* attn = out + (size_t)SEQ*DM;

    hipLaunchKernelGGL(prep_kernel, dim3(5376), dim3(256), 0, stream,
                       q, k, v, wq, wk, wv, wo, wsbf, cosT, sinT);
    hipLaunchKernelGGL(gemm_qkv, dim3(8, 16, 3), dim3(256), 0, stream,
                       wsbf, cosT, sinT);
    hipLaunchKernelGGL(attn_kernel, dim3(32, 16), dim3(256), 0, stream,
                       wsbf, wsbf + (size_t)16*MB, attn);
    hipLaunchKernelGGL(gemm_out, dim3(16, 16), dim3(256), 0, stream,
                       wsbf, bo, out);
}

// Round 3
// 389.157 us; speedup vs baseline: 1.0546x; 1.0546x over previous
//
#include <hip/hip_runtime.h>
#include <hip/hip_bf16.h>

using short8 = __attribute__((ext_vector_type(8))) short;
using f32x4  = __attribute__((ext_vector_type(4))) float;

#define SEQ   2048
#define DM    1024
#define NHEAD 16
#define MB    1048576

// async global->LDS, 16B per lane. LDS dest must be linear in lane (base + lane*16);
// the XOR swizzle is applied to the GLOBAL source address instead (involution =>
// identical LDS image to a ds_write path).
#define GLD16(GP, LP) __builtin_amdgcn_global_load_lds(                      \
    (const __attribute__((address_space(1))) void*)(GP),                     \
    (__attribute__((address_space(3))) void*)(LP), 16, 0, 0)

static __device__ __forceinline__ short f2bf(float f) {
    union { __hip_bfloat16 b; short s; } u;
    u.b = __float2bfloat16(f);
    return u.s;
}
static __device__ __forceinline__ f32x4 mfma_bf16(short8 a, short8 b, f32x4 c) {
    return __builtin_amdgcn_mfma_f32_16x16x32_bf16(a, b, c, 0, 0, 0);
}

// ---------------------------------------------------------------------------
// K0: fp32 -> bf16 conversion of q,k,v,wq,wk,wv,wo into ws (10M elems), plus
// RoPE cos/sin tables [2048][32] fp32.
// ---------------------------------------------------------------------------
__global__ __launch_bounds__(256) void prep_kernel(
    const float* __restrict__ q, const float* __restrict__ k, const float* __restrict__ v,
    const float* __restrict__ wq, const float* __restrict__ wk, const float* __restrict__ wv,
    const float* __restrict__ wo, short* __restrict__ bf,
    float* __restrict__ cosT, float* __restrict__ sinT)
{
    long t = (long)blockIdx.x * 256 + threadIdx.x;
    if (t < 1310720) {                       // 10485760 / 8 elements per thread
        long e0 = t * 8;
        const float* src; long off;
        if      (e0 < 2L*MB) { src = q;  off = e0; }
        else if (e0 < 4L*MB) { src = k;  off = e0 - 2L*MB; }
        else if (e0 < 6L*MB) { src = v;  off = e0 - 4L*MB; }
        else if (e0 < 7L*MB) { src = wq; off = e0 - 6L*MB; }
        else if (e0 < 8L*MB) { src = wk; off = e0 - 7L*MB; }
        else if (e0 < 9L*MB) { src = wv; off = e0 - 8L*MB; }
        else                 { src = wo; off = e0 - 9L*MB; }
        float4 a = *(const float4*)(src + off);
        float4 b = *(const float4*)(src + off + 4);
        short8 o;
        o[0]=f2bf(a.x); o[1]=f2bf(a.y); o[2]=f2bf(a.z); o[3]=f2bf(a.w);
        o[4]=f2bf(b.x); o[5]=f2bf(b.y); o[6]=f2bf(b.z); o[7]=f2bf(b.w);
        *(short8*)(bf + e0) = o;
    } else {
        long tt = t - 1310720;               // < 65536 = 2048*32
        int s = (int)(tt >> 5), j = (int)(tt & 31);
        float invf = __expf(-(float)j * (9.210340371976184f / 32.0f)); // 10000^(-j/32)
        float arg = (float)s * invf;
        cosT[tt] = cosf(arg);
        sinT[tt] = sinf(arg);
    }
}

// ---------------------------------------------------------------------------
// QKV GEMM  C[2048,1024] = X[2048,1024] @ W[1024,1024]^T  (bf16 NT).
// 128x128 block tile, 4 waves 2x2, wave 64x64 (one head wide).
// Double-buffered LDS + global_load_lds prefetch (2-phase pipeline):
//   stage(t+1) -> vmcnt(8) -> barrier -> MFMA(t) -> barrier.
// Epilogue: z<2 (Q,K) applies RoPE in fp32 pre-rounding, writes [h][s][d];
// z==2 (V) writes transposed [h][d][s'] with the key dim PERMUTED within each
// 32-key window: key b*16+g*4+a -> slot g*8+b*4+a (so attn's PV A-fragment is
// uniform-register per lane).
// ---------------------------------------------------------------------------
__global__ __launch_bounds__(256, 2) void gemm_qkv(
    short* __restrict__ wsbf, const float* __restrict__ cosT,
    const float* __restrict__ sinT)
{
    __shared__ short As[2][128 * 64];
    __shared__ short Bs[2][128 * 64];
    const int tid  = threadIdx.x;
    const int lane = tid & 63;
    const int wave = tid >> 6;
    const int q4   = lane >> 4;
    const int l16  = lane & 15;
    const int wm   = wave >> 1;
    const int wn   = wave & 1;
    const int m0   = blockIdx.y * 128;
    const int n0   = blockIdx.x * 128;
    const int z    = blockIdx.z;

    const short* A = wsbf + (size_t)z * (2*MB);
    const short* W = wsbf + 6*(size_t)MB + (size_t)z * MB;

    f32x4 zero = {0.f, 0.f, 0.f, 0.f};
    f32x4 acc[4][4];
    #pragma unroll
    for (int i = 0; i < 4; ++i)
        #pragma unroll
        for (int j = 0; j < 4; ++j) acc[i][j] = zero;

    const int r8 = tid >> 3, c8 = tid & 7;

    auto stage = [&](int k0, int buf) {
        #pragma unroll
        for (int r = 0; r < 4; ++r) {
            int row = r*32 + r8;
            int sw  = c8 ^ (row & 7);
            GLD16(A + (size_t)(m0+row)*1024 + k0 + sw*8, &As[buf][(r*256 + tid)*8]);
            GLD16(W + (size_t)(n0+row)*1024 + k0 + sw*8, &Bs[buf][(r*256 + tid)*8]);
        }
    };

    stage(0, 0);
    for (int t = 0; t < 16; ++t) {
        if (t < 15) stage((t+1)*64, (t+1)&1);
        if (t < 15) asm volatile("s_waitcnt vmcnt(8)" ::: "memory");
        else        asm volatile("s_waitcnt vmcnt(0)" ::: "memory");
        asm volatile("s_barrier" ::: "memory");
        const short* as = As[t&1];
        const short* bs = Bs[t&1];
        #pragma unroll
        for (int kk = 0; kk < 2; ++kk) {
            short8 af[4], bfr[4];
            #pragma unroll
            for (int i = 0; i < 4; ++i) {
                int ra = wm*64 + i*16 + l16;
                af[i]  = *(const short8*)&as[ra*64 + (((kk*4+q4) ^ (ra&7))*8)];
                int rb = wn*64 + i*16 + l16;
                bfr[i] = *(const short8*)&bs[rb*64 + (((kk*4+q4) ^ (rb&7))*8)];
            }
            #pragma unroll
            for (int i = 0; i < 4; ++i)
                #pragma unroll
                for (int j = 0; j < 4; ++j)
                    acc[i][j] = mfma_bf16(af[i], bfr[j], acc[i][j]);
        }
        asm volatile("s_barrier" ::: "memory");   // all waves done reading buf[t&1]
    }

    const int h = (n0 >> 6) + wn;   // wave spans cols [n0+wn*64, +64) = head h
    if (z < 2) {
        short* dst = wsbf + (size_t)(10 + 2*z) * MB;   // [h][s][64]
        #pragma unroll
        for (int i = 0; i < 4; ++i) {
            #pragma unroll
            for (int jj = 0; jj < 4; ++jj) {
                int s = m0 + wm*64 + i*16 + q4*4 + jj;
                float c0 = cosT[(s<<5) + l16],      s0 = sinT[(s<<5) + l16];
                float c1 = cosT[(s<<5) + 16 + l16], s1 = sinT[(s<<5) + 16 + l16];
                float v0 = acc[i][0][jj], v1 = acc[i][1][jj];
                float v2 = acc[i][2][jj], v3 = acc[i][3][jj];
                size_t base = ((size_t)h*SEQ + s)*64;
                dst[base + l16]      = f2bf(v0*c0 - v2*s0);
                dst[base + 16 + l16] = f2bf(v1*c1 - v3*s1);
                dst[base + 32 + l16] = f2bf(v2*c0 + v0*s0);
                dst[base + 48 + l16] = f2bf(v3*c1 + v1*s1);
            }
        }
    } else {
        short* dst = wsbf + (size_t)14 * MB;           // V transposed [h][d][s'], key-permuted
        #pragma unroll
        for (int i = 0; i < 4; ++i)
            #pragma unroll
            for (int j = 0; j < 4; ++j)
                #pragma unroll
                for (int jj = 0; jj < 4; ++jj) {
                    int s  = m0 + wm*64 + i*16 + q4*4 + jj;
                    // window-local perm: key b*16+g*4+a -> slot g*8+b*4+a
                    int sp = (s & ~31) + q4*8 + (i&1)*4 + jj;
                    int d  = j*16 + l16;
                    dst[((size_t)h*64 + d)*SEQ + sp] = f2bf(acc[i][j][jj]);
                }
    }
}

// ---------------------------------------------------------------------------
// Fused attention: block = 64 q-rows x 1 head, wave owns 16 q-rows.
// SWAPPED QK^T: acc = mfma(K_frag, Q_frag) => lane holds S for its OWN q-row
// (q = wave*16+l16), keys nt*16+q4*4+jj. p = exp(S/8) stays IN REGISTERS
// (no Ps LDS). PV: A-frag = uniform-register pack of lane's own p (key dim of
// V pre-permuted in global by gemm_qkv). K double-buffered, V single-buffered,
// counted vmcnt. Sweep 2 reuses swapped layout -> float4 attn stores.
// ---------------------------------------------------------------------------
__global__ __launch_bounds__(256, 2) void attn_kernel(
    const short* __restrict__ wsbf, short* __restrict__ ctxout,
    float* __restrict__ attn)
{
    __shared__ short Qs[64 * 64];
    __shared__ short Ks[2][128 * 64];  // double-buffered K tile [key][d]
    __shared__ short Vs[64 * 128];     // V tile [d][key-slot] (key-permuted)
    const int tid = threadIdx.x, lane = tid & 63, wave = tid >> 6;
    const int q4 = lane >> 4, l16 = lane & 15;
    const int h = blockIdx.y, qt0 = blockIdx.x * 64;
    const short* Qg = wsbf + (size_t)10*MB + ((size_t)h*SEQ + qt0)*64;
    const short* Kg = wsbf + (size_t)12*MB + (size_t)h*SEQ*64;
    const short* Vg = wsbf + (size_t)14*MB + (size_t)h*64*SEQ;

    const int r8  = tid >> 3, c8  = tid & 7;   // K/Q staging coords
    const int r16 = tid >> 4, c16 = tid & 15;  // V staging coords

    auto stageK = [&](int kt, short* buf) {
        #pragma unroll
        for (int r = 0; r < 4; ++r) {
            int row = r*32 + r8;
            int sw  = c8 ^ (row & 7);
            GLD16(Kg + (size_t)(kt*128 + row)*64 + sw*8, buf + (r*256 + tid)*8);
        }
    };
    auto stageV = [&](int kt) {
        #pragma unroll
        for (int r = 0; r < 4; ++r) {
            int row = r*16 + r16;
            int sw  = c16 ^ (row & 7);
            GLD16(Vg + (size_t)row*SEQ + kt*128 + sw*8, &Vs[(r*256 + tid)*8]);
        }
    };

    // prologue: Q + K(0)
    #pragma unroll
    for (int r = 0; r < 2; ++r) {
        int row = r*32 + r8;
        int sw  = c8 ^ (row & 7);
        GLD16(Qg + (size_t)row*64 + sw*8, &Qs[(r*256 + tid)*8]);
    }
    stageK(0, Ks[0]);
    __syncthreads();                     // vmcnt(0) drain + barrier

    const int ra = wave*16 + l16;
    short8 a_q[2];                       // kt-invariant Q fragments
    #pragma unroll
    for (int kk = 0; kk < 2; ++kk)
        a_q[kk] = *(const short8*)&Qs[ra*64 + (((kk*4+q4) ^ (ra&7))*8)];

    f32x4 zero = {0.f, 0.f, 0.f, 0.f};
    f32x4 ctx[4] = {zero, zero, zero, zero};
    float rsl = 0.f;                     // partial rowsum for q = wave*16+l16

    for (int kt = 0; kt < 16; ++kt) {
        const short* Kb = (kt & 1) ? Ks[1] : Ks[0];
        short*       Kn = (kt & 1) ? Ks[0] : Ks[1];
        stageV(kt);                      // needed at mid-barrier
        if (kt < 15) stageK(kt + 1, Kn); // needed at end-barrier
        // S phase (swapped): lane gets S[q=wave*16+l16][key=nt*16+q4*4+jj]
        float p[8][4];
        #pragma unroll
        for (int nt = 0; nt < 8; ++nt) {
            f32x4 acc = zero;
            #pragma unroll
            for (int kk = 0; kk < 2; ++kk) {
                int rb = nt*16 + l16;
                short8 b = *(const short8*)&Kb[rb*64 + (((kk*4+q4) ^ (rb&7))*8)];
                acc = mfma_bf16(b, a_q[kk], acc);    // SWAPPED operands
            }
            #pragma unroll
            for (int jj = 0; jj < 4; ++jj) {
                float pv = __expf(acc[jj] * 0.125f);
                rsl += pv;
                p[nt][jj] = pv;
            }
        }
        // pack PV A-fragments (uniform registers; key perm matches V layout)
        short8 pa[4];
        #pragma unroll
        for (int w = 0; w < 4; ++w) {
            #pragma unroll
            for (int j = 0; j < 4; ++j) { pa[w][j] = f2bf(p[2*w][j]); pa[w][4+j] = f2bf(p[2*w+1][j]); }
        }
        // V = oldest 4 vmem ops of this iteration; K(kt+1) stays in flight.
        if (kt < 15) asm volatile("s_waitcnt vmcnt(4)" ::: "memory");
        else         asm volatile("s_waitcnt vmcnt(0)" ::: "memory");
        asm volatile("s_barrier" ::: "memory");
        // PV phase: ctx[q][d] += P[q][k] V[k][d], k permuted consistently
        __builtin_amdgcn_s_setprio(1);
        #pragma unroll
        for (int w = 0; w < 4; ++w) {
            #pragma unroll
            for (int dt = 0; dt < 4; ++dt) {
                int rv = dt*16 + l16;
                short8 b = *(const short8*)&Vs[rv*128 + (((w*4+q4) ^ (rv&7))*8)];
                ctx[dt] = mfma_bf16(pa[w], b, ctx[dt]);
            }
        }
        __builtin_amdgcn_s_setprio(0);
        // K(kt+1) landed + all LDS reads retired before buffers are rewritten
        asm volatile("s_waitcnt vmcnt(0) lgkmcnt(0)" ::: "memory");
        asm volatile("s_barrier" ::: "memory");
    }

    // rowsum: reduce across the 4 q4-groups sharing each l16 (full row per lane)
    rsl += __shfl_xor(rsl, 16);
    rsl += __shfl_xor(rsl, 32);
    float irs_l = 1.0f / rsl;            // 1/rowsum for q = wave*16+l16
    float irs[4];                        // redistribute to C-layout rows q4*4+jj
    #pragma unroll
    for (int jj = 0; jj < 4; ++jj) irs[jj] = __shfl(irs_l, q4*4 + jj);

    const int qbase = qt0 + wave*16 + q4*4;
    #pragma unroll
    for (int dt = 0; dt < 4; ++dt)
        #pragma unroll
        for (int jj = 0; jj < 4; ++jj)
            ctxout[(size_t)(qbase + jj)*1024 + h*64 + dt*16 + l16] = f2bf(ctx[dt][jj] * irs[jj]);

    // Sweep 2: recompute S (swapped), write normalized attn as float4 rows.
    stageK(0, Ks[0]);                    // Ks[0] last read at kt=14: safe
    asm volatile("s_waitcnt vmcnt(0)" ::: "memory");
    asm volatile("s_barrier" ::: "memory");

    float* arow = attn + (size_t)h*SEQ*SEQ + (size_t)(qt0 + wave*16 + l16)*SEQ;
    for (int kt = 0; kt < 16; ++kt) {
        const short* Kb = (kt & 1) ? Ks[1] : Ks[0];
        short*       Kn = (kt & 1) ? Ks[0] : Ks[1];
        if (kt < 15) stageK(kt + 1, Kn);
        #pragma unroll
        for (int nt = 0; nt < 8; ++nt) {
            f32x4 acc = zero;
            #pragma unroll
            for (int kk = 0; kk < 2; ++kk) {
                int rb = nt*16 + l16;
                short8 b = *(const short8*)&Kb[rb*64 + (((kk*4+q4) ^ (rb&7))*8)];
                acc = mfma_bf16(b, a_q[kk], acc);    // SWAPPED operands
            }
            float4 o;
            o.x = __expf(acc[0] * 0.125f) * irs_l;
            o.y = __expf(acc[1] * 0.125f) * irs_l;
            o.z = __expf(acc[2] * 0.125f) * irs_l;
            o.w = __expf(acc[3] * 0.125f) * irs_l;
            *(float4*)&arow[kt*128 + nt*16 + q4*4] = o;
        }
        // oldest->newest: [<=8 old stores][4 K(kt+1)][8 new stores];
        // vmcnt(8) retires the prefetch K, lets stores keep flowing.
        asm volatile("s_waitcnt vmcnt(8) lgkmcnt(0)" ::: "memory");
        asm volatile("s_barrier" ::: "memory");
    }
}

// ---------------------------------------------------------------------------
// Output projection: out[2048,1024] = ctx[2048,1024] @ wo[1024,1024]^T + b.
// 128x64 block tile (256 blocks for CU fill), 4 waves stacked over rows.
// Double-buffered LDS + global_load_lds prefetch (2-phase pipeline).
// ---------------------------------------------------------------------------
__global__ __launch_bounds__(256, 2) void gemm_out(
    const short* __restrict__ wsbf, const float* __restrict__ bo,
    float* __restrict__ out)
{
    __shared__ short As[2][128 * 64];
    __shared__ short Bs[2][64 * 64];
    const int tid = threadIdx.x, lane = tid & 63, wave = tid >> 6;
    const int q4 = lane >> 4, l16 = lane & 15;
    const int m0 = blockIdx.y * 128, n0 = blockIdx.x * 64;
    const short* A = wsbf + 16*(size_t)MB;    // ctx bf16 [s][1024]
    const short* W = wsbf + 9*(size_t)MB;     // wo bf16 [n][k]

    f32x4 zero = {0.f, 0.f, 0.f, 0.f};
    f32x4 acc[2][4];
    #pragma unroll
    for (int i = 0; i < 2; ++i)
        #pragma unroll
        for (int j = 0; j < 4; ++j) acc[i][j] = zero;

    const int r8 = tid >> 3, c8 = tid & 7;

    auto stage = [&](int k0, int buf) {
        #pragma unroll
        for (int r = 0; r < 4; ++r) {
            int row = r*32 + r8;
            int sw  = c8 ^ (row & 7);
            GLD16(A + (size_t)(m0+row)*1024 + k0 + sw*8, &As[buf][(r*256 + tid)*8]);
        }
        #pragma unroll
        for (int r = 0; r < 2; ++r) {
            int row = r*32 + r8;
            int sw  = c8 ^ (row & 7);
            GLD16(W + (size_t)(n0+row)*1024 + k0 + sw*8, &Bs[buf][(r*256 + tid)*8]);
        }
    };

    stage(0, 0);
    for (int t = 0; t < 16; ++t) {
        if (t < 15) stage((t+1)*64, (t+1)&1);
        if (t < 15) asm volatile("s_waitcnt vmcnt(6)" ::: "memory");
        else        asm volatile("s_waitcnt vmcnt(0)" ::: "memory");
        asm volatile("s_barrier" ::: "memory");
        const short* as = As[t&1];
        const short* bs = Bs[t&1];
        #pragma unroll
        for (int kk = 0; kk < 2; ++kk) {
            short8 af[2], bfr[4];
            #pragma unroll
            for (int i = 0; i < 2; ++i) {
                int ra = wave*32 + i*16 + l16;
                af[i] = *(const short8*)&as[ra*64 + (((kk*4+q4) ^ (ra&7))*8)];
            }
            #pragma unroll
            for (int j = 0; j < 4; ++j) {
                int rb = j*16 + l16;
                bfr[j] = *(const short8*)&bs[rb*64 + (((kk*4+q4) ^ (rb&7))*8)];
            }
            #pragma unroll
            for (int i = 0; i < 2; ++i)
                #pragma unroll
                for (int j = 0; j < 4; ++j)
                    acc[i][j] = mfma_bf16(af[i], bfr[j], acc[i][j]);
        }
        asm volatile("s_barrier" ::: "memory");
    }

    #pragma unroll
    for (int i = 0; i < 2; ++i)
        #pragma unroll
        for (int j = 0; j < 4; ++j)
            #pragma unroll
            for (int jj = 0; jj < 4; ++jj) {
                int gr = m0 + wave*32 + i*16 + q4*4 + jj;
                int gc = n0 + j*16 + l16;
                out[(size_t)gr*1024 + gc] = acc[i][j][jj] + bo[gc];
            }
}

// ---------------------------------------------------------------------------
// ws layout (bf16 elements):
//   0..2M q | 2M..4M k | 4M..6M v | 6M..7M wq | 7M..8M wk | 8M..9M wv | 9M..10M wo
//   10M..12M Qh [h][s][d] | 12M..14M Kh | 14M..16M Vt [h][d][s'] (key-permuted)
//   16M..18M ctx | byte 36MB+: cosT fp32[65536], sinT fp32[65536]
// ---------------------------------------------------------------------------
extern "C" void kernel_launch(void* const* d_in, const int* in_sizes, int n_in,
                              void* d_out, int out_size, void* d_ws, size_t ws_size,
                              hipStream_t stream)
{
    const float* q  = (const float*)d_in[0];
    const float* k  = (const float*)d_in[1];
    const float* v  = (const float*)d_in[2];
    const float* wq = (const float*)d_in[3];
    const float* wk = (const float*)d_in[4];
    const float* wv = (const float*)d_in[5];
    const float* wo = (const float*)d_in[6];
    const float* bo = (const float*)d_in[7];

    short* wsbf = (short*)d_ws;
    float* cosT = (float*)((char*)d_ws + (size_t)36*MB);
    float* sinT = cosT + 65536;
    float* out  = (float*)d_out;
    float* attn = out + (size_t)SEQ*DM;

    hipLaunchKernelGGL(prep_kernel, dim3(5376), dim3(256), 0, stream,
                       q, k, v, wq, wk, wv, wo, wsbf, cosT, sinT);
    hipLaunchKernelGGL(gemm_qkv, dim3(8, 16, 3), dim3(256), 0, stream,
                       wsbf, cosT, sinT);
    hipLaunchKernelGGL(attn_kernel, dim3(32, 16), dim3(256), 0, stream,
                       wsbf, wsbf + (size_t)16*MB, attn);
    hipLaunchKernelGGL(gemm_out, dim3(16, 16), dim3(256), 0, stream,
                       wsbf, bo, out);
}

// Round 4
// 385.934 us; speedup vs baseline: 1.0634x; 1.0083x over previous
//
#include <hip/hip_runtime.h>
#include <hip/hip_bf16.h>

using short8 = __attribute__((ext_vector_type(8))) short;
using f32x4  = __attribute__((ext_vector_type(4))) float;

#define SEQ   2048
#define DM    1024
#define NHEAD 16
#define MB    1048576

// async global->LDS, 16B per lane. LDS dest must be linear in lane (base + lane*16);
// the XOR swizzle is applied to the GLOBAL source address instead (involution =>
// identical LDS image to a ds_write path).
#define GLD16(GP, LP) __builtin_amdgcn_global_load_lds(                      \
    (const __attribute__((address_space(1))) void*)(GP),                     \
    (__attribute__((address_space(3))) void*)(LP), 16, 0, 0)

static __device__ __forceinline__ short f2bf(float f) {
    union { __hip_bfloat16 b; short s; } u;
    u.b = __float2bfloat16(f);
    return u.s;
}
static __device__ __forceinline__ f32x4 mfma_bf16(short8 a, short8 b, f32x4 c) {
    return __builtin_amdgcn_mfma_f32_16x16x32_bf16(a, b, c, 0, 0, 0);
}

// ---------------------------------------------------------------------------
// K0: fp32 -> bf16 conversion of q,k,v,wq,wk,wv,wo into ws (10M elems), plus
// RoPE cos/sin tables [2048][32] fp32.
// ---------------------------------------------------------------------------
__global__ __launch_bounds__(256) void prep_kernel(
    const float* __restrict__ q, const float* __restrict__ k, const float* __restrict__ v,
    const float* __restrict__ wq, const float* __restrict__ wk, const float* __restrict__ wv,
    const float* __restrict__ wo, short* __restrict__ bf,
    float* __restrict__ cosT, float* __restrict__ sinT)
{
    long t = (long)blockIdx.x * 256 + threadIdx.x;
    if (t < 1310720) {                       // 10485760 / 8 elements per thread
        long e0 = t * 8;
        const float* src; long off;
        if      (e0 < 2L*MB) { src = q;  off = e0; }
        else if (e0 < 4L*MB) { src = k;  off = e0 - 2L*MB; }
        else if (e0 < 6L*MB) { src = v;  off = e0 - 4L*MB; }
        else if (e0 < 7L*MB) { src = wq; off = e0 - 6L*MB; }
        else if (e0 < 8L*MB) { src = wk; off = e0 - 7L*MB; }
        else if (e0 < 9L*MB) { src = wv; off = e0 - 8L*MB; }
        else                 { src = wo; off = e0 - 9L*MB; }
        float4 a = *(const float4*)(src + off);
        float4 b = *(const float4*)(src + off + 4);
        short8 o;
        o[0]=f2bf(a.x); o[1]=f2bf(a.y); o[2]=f2bf(a.z); o[3]=f2bf(a.w);
        o[4]=f2bf(b.x); o[5]=f2bf(b.y); o[6]=f2bf(b.z); o[7]=f2bf(b.w);
        *(short8*)(bf + e0) = o;
    } else {
        long tt = t - 1310720;               // < 65536 = 2048*32
        int s = (int)(tt >> 5), j = (int)(tt & 31);
        float invf = __expf(-(float)j * (9.210340371976184f / 32.0f)); // 10000^(-j/32)
        float arg = (float)s * invf;
        cosT[tt] = cosf(arg);
        sinT[tt] = sinf(arg);
    }
}

// ---------------------------------------------------------------------------
// QKV GEMM  C[2048,1024] = X[2048,1024] @ W[1024,1024]^T  (bf16 NT).
// 128x128 block tile, 4 waves 2x2, wave 64x64 (one head wide).
// Double-buffered LDS + global_load_lds prefetch (2-phase pipeline).
// Epilogue: z<2 (Q,K) applies RoPE in fp32 pre-rounding, writes [h][s][d];
// z==2 (V) writes transposed [h][d][s'] with the key dim PERMUTED within each
// 32-key window: key b*16+g*4+a -> slot g*8+b*4+a.
// ---------------------------------------------------------------------------
__global__ __launch_bounds__(256, 2) void gemm_qkv(
    short* __restrict__ wsbf, const float* __restrict__ cosT,
    const float* __restrict__ sinT)
{
    __shared__ short As[2][128 * 64];
    __shared__ short Bs[2][128 * 64];
    const int tid  = threadIdx.x;
    const int lane = tid & 63;
    const int wave = tid >> 6;
    const int q4   = lane >> 4;
    const int l16  = lane & 15;
    const int wm   = wave >> 1;
    const int wn   = wave & 1;
    const int m0   = blockIdx.y * 128;
    const int n0   = blockIdx.x * 128;
    const int z    = blockIdx.z;

    const short* A = wsbf + (size_t)z * (2*MB);
    const short* W = wsbf + 6*(size_t)MB + (size_t)z * MB;

    f32x4 zero = {0.f, 0.f, 0.f, 0.f};
    f32x4 acc[4][4];
    #pragma unroll
    for (int i = 0; i < 4; ++i)
        #pragma unroll
        for (int j = 0; j < 4; ++j) acc[i][j] = zero;

    const int r8 = tid >> 3, c8 = tid & 7;

    auto stage = [&](int k0, int buf) {
        #pragma unroll
        for (int r = 0; r < 4; ++r) {
            int row = r*32 + r8;
            int sw  = c8 ^ (row & 7);
            GLD16(A + (size_t)(m0+row)*1024 + k0 + sw*8, &As[buf][(r*256 + tid)*8]);
            GLD16(W + (size_t)(n0+row)*1024 + k0 + sw*8, &Bs[buf][(r*256 + tid)*8]);
        }
    };

    stage(0, 0);
    for (int t = 0; t < 16; ++t) {
        if (t < 15) stage((t+1)*64, (t+1)&1);
        if (t < 15) asm volatile("s_waitcnt vmcnt(8)" ::: "memory");
        else        asm volatile("s_waitcnt vmcnt(0)" ::: "memory");
        asm volatile("s_barrier" ::: "memory");
        const short* as = As[t&1];
        const short* bs = Bs[t&1];
        #pragma unroll
        for (int kk = 0; kk < 2; ++kk) {
            short8 af[4], bfr[4];
            #pragma unroll
            for (int i = 0; i < 4; ++i) {
                int ra = wm*64 + i*16 + l16;
                af[i]  = *(const short8*)&as[ra*64 + (((kk*4+q4) ^ (ra&7))*8)];
                int rb = wn*64 + i*16 + l16;
                bfr[i] = *(const short8*)&bs[rb*64 + (((kk*4+q4) ^ (rb&7))*8)];
            }
            #pragma unroll
            for (int i = 0; i < 4; ++i)
                #pragma unroll
                for (int j = 0; j < 4; ++j)
                    acc[i][j] = mfma_bf16(af[i], bfr[j], acc[i][j]);
        }
        asm volatile("s_barrier" ::: "memory");   // all waves done reading buf[t&1]
    }

    const int h = (n0 >> 6) + wn;   // wave spans cols [n0+wn*64, +64) = head h
    if (z < 2) {
        short* dst = wsbf + (size_t)(10 + 2*z) * MB;   // [h][s][64]
        #pragma unroll
        for (int i = 0; i < 4; ++i) {
            #pragma unroll
            for (int jj = 0; jj < 4; ++jj) {
                int s = m0 + wm*64 + i*16 + q4*4 + jj;
                float c0 = cosT[(s<<5) + l16],      s0 = sinT[(s<<5) + l16];
                float c1 = cosT[(s<<5) + 16 + l16], s1 = sinT[(s<<5) + 16 + l16];
                float v0 = acc[i][0][jj], v1 = acc[i][1][jj];
                float v2 = acc[i][2][jj], v3 = acc[i][3][jj];
                size_t base = ((size_t)h*SEQ + s)*64;
                dst[base + l16]      = f2bf(v0*c0 - v2*s0);
                dst[base + 16 + l16] = f2bf(v1*c1 - v3*s1);
                dst[base + 32 + l16] = f2bf(v2*c0 + v0*s0);
                dst[base + 48 + l16] = f2bf(v3*c1 + v1*s1);
            }
        }
    } else {
        short* dst = wsbf + (size_t)14 * MB;           // V transposed [h][d][s'], key-permuted
        #pragma unroll
        for (int i = 0; i < 4; ++i)
            #pragma unroll
            for (int j = 0; j < 4; ++j)
                #pragma unroll
                for (int jj = 0; jj < 4; ++jj) {
                    int s  = m0 + wm*64 + i*16 + q4*4 + jj;
                    // window-local perm: key b*16+g*4+a -> slot g*8+b*4+a
                    int sp = (s & ~31) + q4*8 + (i&1)*4 + jj;
                    int d  = j*16 + l16;
                    dst[((size_t)h*64 + d)*SEQ + sp] = f2bf(acc[i][j][jj]);
                }
    }
}

// ---------------------------------------------------------------------------
// Fused attention: block = 128 q-rows x 1 head, 512 threads (8 waves), wave
// owns 16 q-rows. Grid = 256 blocks = 1/CU (zero tail). XCD-affine swizzle:
// bid%8 (= XCD under round-robin dispatch) selects a 2-head group, so each
// XCD's 32 blocks share 2 heads -> K/V working set 1 MB << 4 MB L2.
// SWAPPED QK^T: lane holds S for its OWN q-row; p stays in registers; PV
// A-frag is a uniform-register pack (V key-permuted in global). K dbuf,
// counted vmcnt. Sweep 2: recompute S, float4 normalized attn stores.
// ---------------------------------------------------------------------------
__global__ __launch_bounds__(512, 2) void attn_kernel(
    const short* __restrict__ wsbf, short* __restrict__ ctxout,
    float* __restrict__ attn)
{
    __shared__ short Qs[128 * 64];
    __shared__ short Ks[2][128 * 64];  // double-buffered K tile [key][d]
    __shared__ short Vs[64 * 128];     // V tile [d][key-slot] (key-permuted)
    const int tid = threadIdx.x, lane = tid & 63, wave = tid >> 6;
    const int q4 = lane >> 4, l16 = lane & 15;
    // XCD-affine decode: blocks with bid%8==x -> XCD x -> heads {2x, 2x+1}
    const int bid = blockIdx.x;
    const int grp = bid & 7, inner = bid >> 3;
    const int h   = grp*2 + (inner & 1);
    const int qt0 = (inner >> 1) * 128;
    const short* Qg = wsbf + (size_t)10*MB + ((size_t)h*SEQ + qt0)*64;
    const short* Kg = wsbf + (size_t)12*MB + (size_t)h*SEQ*64;
    const short* Vg = wsbf + (size_t)14*MB + (size_t)h*64*SEQ;

    const int r8  = tid >> 3, c8  = tid & 7;   // K/Q staging coords
    const int r16 = tid >> 4, c16 = tid & 15;  // V staging coords

    auto stageK = [&](int kt, short* buf) {
        #pragma unroll
        for (int r = 0; r < 2; ++r) {          // 128x64 tile, 512 threads
            int row = r*64 + r8;
            int sw  = c8 ^ (row & 7);
            GLD16(Kg + (size_t)(kt*128 + row)*64 + sw*8, buf + (r*512 + tid)*8);
        }
    };
    auto stageV = [&](int kt) {
        #pragma unroll
        for (int r = 0; r < 2; ++r) {          // 64x128 tile
            int row = r*32 + r16;
            int sw  = c16 ^ (row & 7);
            GLD16(Vg + (size_t)row*SEQ + kt*128 + sw*8, &Vs[(r*512 + tid)*8]);
        }
    };

    // prologue: Q + K(0)
    #pragma unroll
    for (int r = 0; r < 2; ++r) {              // 128x64 Q tile
        int row = r*64 + r8;
        int sw  = c8 ^ (row & 7);
        GLD16(Qg + (size_t)row*64 + sw*8, &Qs[(r*512 + tid)*8]);
    }
    stageK(0, Ks[0]);
    __syncthreads();                     // vmcnt(0) drain + barrier

    const int ra = wave*16 + l16;        // this wave's q-row (0..127)
    short8 a_q[2];                       // kt-invariant Q fragments
    #pragma unroll
    for (int kk = 0; kk < 2; ++kk)
        a_q[kk] = *(const short8*)&Qs[ra*64 + (((kk*4+q4) ^ (ra&7))*8)];

    f32x4 zero = {0.f, 0.f, 0.f, 0.f};
    f32x4 ctx[4] = {zero, zero, zero, zero};
    float rsl = 0.f;                     // partial rowsum for q = wave*16+l16

    for (int kt = 0; kt < 16; ++kt) {
        const short* Kb = (kt & 1) ? Ks[1] : Ks[0];
        short*       Kn = (kt & 1) ? Ks[0] : Ks[1];
        stageV(kt);                      // needed at mid-barrier (2 loads/wave)
        if (kt < 15) stageK(kt + 1, Kn); // needed at end-barrier (2 loads/wave)
        // S phase (swapped): lane gets S[q=wave*16+l16][key=nt*16+q4*4+jj]
        float p[8][4];
        #pragma unroll
        for (int nt = 0; nt < 8; ++nt) {
            f32x4 acc = zero;
            #pragma unroll
            for (int kk = 0; kk < 2; ++kk) {
                int rb = nt*16 + l16;
                short8 b = *(const short8*)&Kb[rb*64 + (((kk*4+q4) ^ (rb&7))*8)];
                acc = mfma_bf16(b, a_q[kk], acc);    // SWAPPED operands
            }
            #pragma unroll
            for (int jj = 0; jj < 4; ++jj) {
                float pv = __expf(acc[jj] * 0.125f);
                rsl += pv;
                p[nt][jj] = pv;
            }
        }
        // pack PV A-fragments (uniform registers; key perm matches V layout)
        short8 pa[4];
        #pragma unroll
        for (int w = 0; w < 4; ++w) {
            #pragma unroll
            for (int j = 0; j < 4; ++j) { pa[w][j] = f2bf(p[2*w][j]); pa[w][4+j] = f2bf(p[2*w+1][j]); }
        }
        // V = oldest 2 vmem ops of this iteration; K(kt+1) stays in flight.
        if (kt < 15) asm volatile("s_waitcnt vmcnt(2)" ::: "memory");
        else         asm volatile("s_waitcnt vmcnt(0)" ::: "memory");
        asm volatile("s_barrier" ::: "memory");
        // PV phase: ctx[q][d] += P[q][k] V[k][d], k permuted consistently
        __builtin_amdgcn_s_setprio(1);
        #pragma unroll
        for (int w = 0; w < 4; ++w) {
            #pragma unroll
            for (int dt = 0; dt < 4; ++dt) {
                int rv = dt*16 + l16;
                short8 b = *(const short8*)&Vs[rv*128 + (((w*4+q4) ^ (rv&7))*8)];
                ctx[dt] = mfma_bf16(pa[w], b, ctx[dt]);
            }
        }
        __builtin_amdgcn_s_setprio(0);
        // K(kt+1) landed + all LDS reads retired before buffers are rewritten
        asm volatile("s_waitcnt vmcnt(0) lgkmcnt(0)" ::: "memory");
        asm volatile("s_barrier" ::: "memory");
    }

    // rowsum: reduce across the 4 q4-groups sharing each l16 (full row per lane)
    rsl += __shfl_xor(rsl, 16);
    rsl += __shfl_xor(rsl, 32);
    float irs_l = 1.0f / rsl;            // 1/rowsum for q = wave*16+l16
    float irs[4];                        // redistribute to C-layout rows q4*4+jj
    #pragma unroll
    for (int jj = 0; jj < 4; ++jj) irs[jj] = __shfl(irs_l, q4*4 + jj);

    const int qbase = qt0 + wave*16 + q4*4;
    #pragma unroll
    for (int dt = 0; dt < 4; ++dt)
        #pragma unroll
        for (int jj = 0; jj < 4; ++jj)
            ctxout[(size_t)(qbase + jj)*1024 + h*64 + dt*16 + l16] = f2bf(ctx[dt][jj] * irs[jj]);

    // Sweep 2: recompute S (swapped), write normalized attn as float4 rows.
    stageK(0, Ks[0]);                    // Ks[0] last read at kt=14: safe
    asm volatile("s_waitcnt vmcnt(0)" ::: "memory");
    asm volatile("s_barrier" ::: "memory");

    float* arow = attn + (size_t)h*SEQ*SEQ + (size_t)(qt0 + wave*16 + l16)*SEQ;
    for (int kt = 0; kt < 16; ++kt) {
        const short* Kb = (kt & 1) ? Ks[1] : Ks[0];
        short*       Kn = (kt & 1) ? Ks[0] : Ks[1];
        if (kt < 15) stageK(kt + 1, Kn);
        #pragma unroll
        for (int nt = 0; nt < 8; ++nt) {
            f32x4 acc = zero;
            #pragma unroll
            for (int kk = 0; kk < 2; ++kk) {
                int rb = nt*16 + l16;
                short8 b = *(const short8*)&Kb[rb*64 + (((kk*4+q4) ^ (rb&7))*8)];
                acc = mfma_bf16(b, a_q[kk], acc);    // SWAPPED operands
            }
            float4 o;
            o.x = __expf(acc[0] * 0.125f) * irs_l;
            o.y = __expf(acc[1] * 0.125f) * irs_l;
            o.z = __expf(acc[2] * 0.125f) * irs_l;
            o.w = __expf(acc[3] * 0.125f) * irs_l;
            *(float4*)&arow[kt*128 + nt*16 + q4*4] = o;
        }
        // oldest->newest: [<=8 old stores][2 K(kt+1)][8 new stores];
        // vmcnt(8) retires the prefetch K, lets stores keep flowing.
        asm volatile("s_waitcnt vmcnt(8) lgkmcnt(0)" ::: "memory");
        asm volatile("s_barrier" ::: "memory");
    }
}

// ---------------------------------------------------------------------------
// Output projection: out[2048,1024] = ctx[2048,1024] @ wo[1024,1024]^T + b.
// 128x64 block tile (256 blocks for CU fill), 4 waves stacked over rows.
// Double-buffered LDS + global_load_lds prefetch (2-phase pipeline).
// ---------------------------------------------------------------------------
__global__ __launch_bounds__(256, 2) void gemm_out(
    const short* __restrict__ wsbf, const float* __restrict__ bo,
    float* __restrict__ out)
{
    __shared__ short As[2][128 * 64];
    __shared__ short Bs[2][64 * 64];
    const int tid = threadIdx.x, lane = tid & 63, wave = tid >> 6;
    const int q4 = lane >> 4, l16 = lane & 15;
    const int m0 = blockIdx.y * 128, n0 = blockIdx.x * 64;
    const short* A = wsbf + 16*(size_t)MB;    // ctx bf16 [s][1024]
    const short* W = wsbf + 9*(size_t)MB;     // wo bf16 [n][k]

    f32x4 zero = {0.f, 0.f, 0.f, 0.f};
    f32x4 acc[2][4];
    #pragma unroll
    for (int i = 0; i < 2; ++i)
        #pragma unroll
        for (int j = 0; j < 4; ++j) acc[i][j] = zero;

    const int r8 = tid >> 3, c8 = tid & 7;

    auto stage = [&](int k0, int buf) {
        #pragma unroll
        for (int r = 0; r < 4; ++r) {
            int row = r*32 + r8;
            int sw  = c8 ^ (row & 7);
            GLD16(A + (size_t)(m0+row)*1024 + k0 + sw*8, &As[buf][(r*256 + tid)*8]);
        }
        #pragma unroll
        for (int r = 0; r < 2; ++r) {
            int row = r*32 + r8;
            int sw  = c8 ^ (row & 7);
            GLD16(W + (size_t)(n0+row)*1024 + k0 + sw*8, &Bs[buf][(r*256 + tid)*8]);
        }
    };

    stage(0, 0);
    for (int t = 0; t < 16; ++t) {
        if (t < 15) stage((t+1)*64, (t+1)&1);
        if (t < 15) asm volatile("s_waitcnt vmcnt(6)" ::: "memory");
        else        asm volatile("s_waitcnt vmcnt(0)" ::: "memory");
        asm volatile("s_barrier" ::: "memory");
        const short* as = As[t&1];
        const short* bs = Bs[t&1];
        #pragma unroll
        for (int kk = 0; kk < 2; ++kk) {
            short8 af[2], bfr[4];
            #pragma unroll
            for (int i = 0; i < 2; ++i) {
                int ra = wave*32 + i*16 + l16;
                af[i] = *(const short8*)&as[ra*64 + (((kk*4+q4) ^ (ra&7))*8)];
            }
            #pragma unroll
            for (int j = 0; j < 4; ++j) {
                int rb = j*16 + l16;
                bfr[j] = *(const short8*)&bs[rb*64 + (((kk*4+q4) ^ (rb&7))*8)];
            }
            #pragma unroll
            for (int i = 0; i < 2; ++i)
                #pragma unroll
                for (int j = 0; j < 4; ++j)
                    acc[i][j] = mfma_bf16(af[i], bfr[j], acc[i][j]);
        }
        asm volatile("s_barrier" ::: "memory");
    }

    #pragma unroll
    for (int i = 0; i < 2; ++i)
        #pragma unroll
        for (int j = 0; j < 4; ++j)
            #pragma unroll
            for (int jj = 0; jj < 4; ++jj) {
                int gr = m0 + wave*32 + i*16 + q4*4 + jj;
                int gc = n0 + j*16 + l16;
                out[(size_t)gr*1024 + gc] = acc[i][j][jj] + bo[gc];
            }
}

// ---------------------------------------------------------------------------
// ws layout (bf16 elements):
//   0..2M q | 2M..4M k | 4M..6M v | 6M..7M wq | 7M..8M wk | 8M..9M wv | 9M..10M wo
//   10M..12M Qh [h][s][d] | 12M..14M Kh | 14M..16M Vt [h][d][s'] (key-permuted)
//   16M..18M ctx | byte 36MB+: cosT fp32[65536], sinT fp32[65536]
// ---------------------------------------------------------------------------
extern "C" void kernel_launch(void* const* d_in, const int* in_sizes, int n_in,
                              void* d_out, int out_size, void* d_ws, size_t ws_size,
                              hipStream_t stream)
{
    const float* q  = (const float*)d_in[0];
    const float* k  = (const float*)d_in[1];
    const float* v  = (const float*)d_in[2];
    const float* wq = (const float*)d_in[3];
    const float* wk = (const float*)d_in[4];
    const float* wv = (const float*)d_in[5];
    const float* wo = (const float*)d_in[6];
    const float* bo = (const float*)d_in[7];

    short* wsbf = (short*)d_ws;
    float* cosT = (float*)((char*)d_ws + (size_t)36*MB);
    float* sinT = cosT + 65536;
    float* out  = (float*)d_out;
    float* attn = out + (size_t)SEQ*DM;

    hipLaunchKernelGGL(prep_kernel, dim3(5376), dim3(256), 0, stream,
                       q, k, v, wq, wk, wv, wo, wsbf, cosT, sinT);
    hipLaunchKernelGGL(gemm_qkv, dim3(8, 16, 3), dim3(256), 0, stream,
                       wsbf, cosT, sinT);
    hipLaunchKernelGGL(attn_kernel, dim3(256), dim3(512), 0, stream,
                       wsbf, wsbf + (size_t)16*MB, attn);
    hipLaunchKernelGGL(gemm_out, dim3(16, 16), dim3(256), 0, stream,
                       wsbf, bo, out);
}